// Round 23
// baseline (174.681 us; speedup 1.0000x reference)
//
#include <hip/hip_runtime.h>
#include <hip/hip_bf16.h>
#include <hip/hip_fp16.h>

#define N_NODES 100000
#define N_EDGES 3200000
#define IN_DIM  256
#define OUT_DIM 64
#define NBUK2   512
#define BRANGE  196                       // 512*196 = 100352 >= 100000
#define BINBLK  256                       // blocks in hist/bin (mapping MUST match)
#define CHUNK   (N_EDGES / BINBLK)        // 12500 (divisible by 4)
#define GRP     (CHUNK / 4)               // 3125 4-edge groups per block
#define HTOT    (NBUK2 * BINBLK)          // 131072
#define CAP     12288                     // LDS staging entries (48KB); mean 6250
#define SCLS_RANGE 12500                  // src-class granularity (8 classes)

typedef __attribute__((ext_vector_type(8))) short short8;
typedef __attribute__((ext_vector_type(4))) float float4v;
typedef __attribute__((ext_vector_type(2))) float floatx2;
typedef __attribute__((ext_vector_type(4))) unsigned int uint4v;
typedef __attribute__((ext_vector_type(2))) long long ll2;
typedef __attribute__((ext_vector_type(4))) int int4v;

// ---------------------------------------------------------------------------
// fp8 e4m3 pack/unpack (HW cvt on gfx950, software fallback)
// ---------------------------------------------------------------------------
__device__ __forceinline__ unsigned int enc_fp8_sw(float v) {
    unsigned int u = __float_as_uint(v);
    unsigned int s = (u >> 24) & 0x80u;
    unsigned int mag = u & 0x7fffffffu;
    unsigned int q;
    if (mag >= 0x43e00000u) q = 0x7e;
    else if (mag < 0x3c800000u) {
        float av = __uint_as_float(mag);
        q = (unsigned int)(av * 512.0f + 0.5f);
    } else {
        unsigned int mr = mag + 0x00080000u;
        unsigned int e = (mr >> 23) - 127 + 7;
        unsigned int m = (mr >> 20) & 7;
        q = (e << 3) | m;
        if (q > 0x7e) q = 0x7e;
    }
    return s | q;
}
__device__ __forceinline__ float dec_fp8_sw(unsigned int b) {
    unsigned int s = (b & 0x80u) << 24;
    unsigned int e = (b >> 3) & 15u, m = b & 7u;
    float f = (e == 0) ? (float)m * 0.001953125f
                       : __uint_as_float(((e + 120u) << 23) | (m << 20));
    return __uint_as_float(__float_as_uint(f) | s);
}

__device__ __forceinline__ unsigned short pack_fp8x2(float lo, float hi) {
#if __has_builtin(__builtin_amdgcn_cvt_pk_fp8_f32)
    int p = __builtin_amdgcn_cvt_pk_fp8_f32(lo, hi, 0, false);
    return (unsigned short)((unsigned int)p & 0xffffu);
#else
    return (unsigned short)(enc_fp8_sw(lo) | (enc_fp8_sw(hi) << 8));
#endif
}
template<bool HI>
__device__ __forceinline__ floatx2 cvt2(unsigned int w) {
#if __has_builtin(__builtin_amdgcn_cvt_pk_f32_fp8)
    return __builtin_amdgcn_cvt_pk_f32_fp8((int)w, HI);
#else
    unsigned int g = HI ? (w >> 16) : (w & 0xffffu);
    floatx2 r; r[0] = dec_fp8_sw(g & 0xffu); r[1] = dec_fp8_sw((g >> 8) & 0xffu);
    return r;
#endif
}

// ---------------------------------------------------------------------------
// Inline dtype detection. int64 input (values < 2^31) -> all odd 32-bit words
// of the first 8192 are 0.
// ---------------------------------------------------------------------------
__device__ __forceinline__ bool detect_is64(const void* ei) {
    int tid = threadIdx.x;
    const int* e32 = (const int*)ei;
    int found = 0;
    for (int w = 2 * tid + 1; w < 8192; w += 2 * blockDim.x)
        found |= (e32[w] != 0);
    return __syncthreads_or(found) == 0;
}

// ---------------------------------------------------------------------------
// Kernel 1: per-(bucket,block) histogram of dst. 4 edges/lane via 16B loads.
// ---------------------------------------------------------------------------
__global__ __launch_bounds__(256) void hist_kernel(
    const void* __restrict__ ei, int* __restrict__ hist) {
    __shared__ int lh[NBUK2];
    bool is64 = detect_is64(ei);
    int tid = threadIdx.x;
    for (int b = tid; b < NBUK2; b += 256) lh[b] = 0;
    __syncthreads();
    const int g0 = blockIdx.x * GRP, g1 = g0 + GRP;
    if (is64) {
        const long long* dptr = (const long long*)ei + N_EDGES;
        for (int g = g0 + tid; g < g1; g += 256) {
            int e = g * 4;
            ll2 d01 = *(const ll2*)(dptr + e);
            ll2 d23 = *(const ll2*)(dptr + e + 2);
            atomicAdd(&lh[(unsigned)(int)d01[0] / BRANGE], 1);
            atomicAdd(&lh[(unsigned)(int)d01[1] / BRANGE], 1);
            atomicAdd(&lh[(unsigned)(int)d23[0] / BRANGE], 1);
            atomicAdd(&lh[(unsigned)(int)d23[1] / BRANGE], 1);
        }
    } else {
        const int* dptr = (const int*)ei + N_EDGES;
        for (int g = g0 + tid; g < g1; g += 256) {
            int e = g * 4;
            int4v d = *(const int4v*)(dptr + e);
            atomicAdd(&lh[(unsigned)d[0] / BRANGE], 1);
            atomicAdd(&lh[(unsigned)d[1] / BRANGE], 1);
            atomicAdd(&lh[(unsigned)d[2] / BRANGE], 1);
            atomicAdd(&lh[(unsigned)d[3] / BRANGE], 1);
        }
    }
    __syncthreads();
    for (int b = tid; b < NBUK2; b += 256) hist[b * BINBLK + blockIdx.x] = lh[b];
}

// ---------------------------------------------------------------------------
// Kernels 2a/2b/2c: exclusive scan of hist[HTOT] -> pos. hscan2 fused with
// prep_w (block 0 = scan; blocks 1..12 = weight prep, fragment-linear layout).
// ---------------------------------------------------------------------------
__global__ __launch_bounds__(256) void hscan1_kernel(const int* __restrict__ hist,
                                                     int* __restrict__ hb) {
    __shared__ int red[256];
    int tid = threadIdx.x;
    red[tid] = hist[blockIdx.x * 256 + tid];
    __syncthreads();
    #pragma unroll
    for (int off = 128; off > 0; off >>= 1) {
        if (tid < off) red[tid] += red[tid + off];
        __syncthreads();
    }
    if (tid == 0) hb[blockIdx.x] = red[0];
}

__global__ __launch_bounds__(512) void hscan2_prep_kernel(
    int* __restrict__ hb,
    const float* __restrict__ Whp, const float* __restrict__ bhp,
    const float* __restrict__ Wlp, const float* __restrict__ blp,
    const float* __restrict__ Wi,  const float* __restrict__ bi,
    __hip_bfloat16* __restrict__ Wtf, float* __restrict__ biasAll) {
    __shared__ int sh[512];
    int tid = threadIdx.x;
    if (blockIdx.x == 0) {
        int v = hb[tid];
        sh[tid] = v;
        __syncthreads();
        int val = v;
        #pragma unroll
        for (int off = 1; off < 512; off <<= 1) {
            int t = (tid >= off) ? sh[tid - off] : 0;
            __syncthreads();
            val += t;
            sh[tid] = val;
            __syncthreads();
        }
        hb[tid] = val - v;                // exclusive block prefix
    } else {
        int gid = (blockIdx.x - 1) * 512 + tid;      // 0..6143 == 96*64-1
        int frag = gid >> 6, j = gid & 63;
        int kk = frag / 12, slot = frag - kk * 12;
        int cl = j >> 2, kh = j & 3;
        int col = slot * 16 + cl;
        const float* W = (col < 64) ? Whp : (col < 128) ? Wlp : Wi;
        int c2 = col & 63;
        int k0 = kk * 32 + kh * 8;
        unsigned short tmp[8];
        #pragma unroll
        for (int i = 0; i < 8; ++i) {
            __hip_bfloat16 bv = __float2bfloat16(W[(k0 + i) * 64 + c2]);
            tmp[i] = *(unsigned short*)&bv;
        }
        *(short8*)((unsigned short*)Wtf + (size_t)gid * 8) = *(short8*)tmp;
        if (gid < 192) {
            const float* b = (gid < 64) ? bhp : (gid < 128) ? blp : bi;
            biasAll[gid] = b[gid & 63];
        }
    }
}

__global__ __launch_bounds__(256) void hscan3_kernel(const int* __restrict__ hist,
                                                     const int* __restrict__ hb,
                                                     int* __restrict__ pos) {
    __shared__ int sh[256];
    int tid = threadIdx.x;
    int i = blockIdx.x * 256 + tid;
    int v = hist[i];
    sh[tid] = v;
    __syncthreads();
    int val = v;
    #pragma unroll
    for (int off = 1; off < 256; off <<= 1) {
        int t = (tid >= off) ? sh[tid - off] : 0;
        __syncthreads();
        val += t;
        sh[tid] = val;
        __syncthreads();
    }
    pos[i] = hb[blockIdx.x] + val - v;
    if (i == HTOT - 1) pos[HTOT] = N_EDGES;
}

// ---------------------------------------------------------------------------
// Kernel 3: bin edges by dst-bucket via LDS cursors. 4 edges/lane via 16B
// vector loads. 4B packed record src | lnode<<24.
// ---------------------------------------------------------------------------
__global__ __launch_bounds__(256) void bin_kernel(
    const void* __restrict__ ei,
    const int* __restrict__ pos, unsigned int* __restrict__ binned) {
    __shared__ int lcur[NBUK2];
    bool is64 = detect_is64(ei);
    int tid = threadIdx.x;
    for (int b = tid; b < NBUK2; b += 256) lcur[b] = pos[b * BINBLK + blockIdx.x];
    __syncthreads();
    const int g0 = blockIdx.x * GRP, g1 = g0 + GRP;
    if (is64) {
        const long long* sptr = (const long long*)ei;
        const long long* dptr = sptr + N_EDGES;
        for (int g = g0 + tid; g < g1; g += 256) {
            int e = g * 4;
            ll2 s01 = *(const ll2*)(sptr + e);
            ll2 s23 = *(const ll2*)(sptr + e + 2);
            ll2 d01 = *(const ll2*)(dptr + e);
            ll2 d23 = *(const ll2*)(dptr + e + 2);
            int ss[4] = {(int)s01[0], (int)s01[1], (int)s23[0], (int)s23[1]};
            int dd[4] = {(int)d01[0], (int)d01[1], (int)d23[0], (int)d23[1]};
            #pragma unroll
            for (int j = 0; j < 4; ++j) {
                int b = (int)((unsigned)dd[j] / BRANGE);
                int lnode = dd[j] - b * BRANGE;
                int p = atomicAdd(&lcur[b], 1);
                binned[p] = (unsigned)ss[j] | ((unsigned)lnode << 24);
            }
        }
    } else {
        const int* sptr = (const int*)ei;
        const int* dptr = sptr + N_EDGES;
        for (int g = g0 + tid; g < g1; g += 256) {
            int e = g * 4;
            int4v s = *(const int4v*)(sptr + e);
            int4v d = *(const int4v*)(dptr + e);
            #pragma unroll
            for (int j = 0; j < 4; ++j) {
                int b = (int)((unsigned)d[j] / BRANGE);
                int lnode = d[j] - b * BRANGE;
                int p = atomicAdd(&lcur[b], 1);
                binned[p] = (unsigned)s[j] | ((unsigned)lnode << 24);
            }
        }
    }
}

// ---------------------------------------------------------------------------
// Kernel 4: per-bucket CSR build fully in LDS. Sort key = lnode*8 + src-class.
// 4B packed input records. Also emits offs/isq/dinv.
// ---------------------------------------------------------------------------
__global__ __launch_bounds__(256) void fill_kernel(
    const unsigned int* __restrict__ binned, const int* __restrict__ pos,
    unsigned int* __restrict__ csr, int* __restrict__ offs,
    float* __restrict__ isq, float* __restrict__ dinv) {
    __shared__ int ldeg2[BRANGE * 8];     // per (node,src-class) counts->cursors
    __shared__ int lpre[256];
    __shared__ unsigned int stag[CAP];

    int b = blockIdx.x;
    int ns = b * BRANGE;
    if (ns >= N_NODES) return;
    int ne = ns + BRANGE; if (ne > N_NODES) ne = N_NODES;
    int nn = ne - ns;
    int nsb = nn * 8;                     // sub-bucket count
    int lo = pos[b * BINBLK];
    int hi = pos[(b + 1) * BINBLK];
    int nb = hi - lo;
    int tid = threadIdx.x;

    for (int i = tid; i < nsb; i += 256) ldeg2[i] = 0;
    __syncthreads();
    for (int e = lo + tid; e < hi; e += 256) {
        unsigned int r = binned[e];
        atomicAdd(&ldeg2[(r >> 24) * 8 + (r & 0xffffffu) / SCLS_RANGE], 1);
    }
    __syncthreads();

    // block-wide exclusive scan over nsb sub-buckets (7 elems/thread)
    int base = tid * 7;
    int loc[7];
    int s = 0;
    #pragma unroll
    for (int j = 0; j < 7; ++j) {
        int idx = base + j;
        int v = (idx < nsb) ? ldeg2[idx] : 0;
        loc[j] = s;
        s += v;
    }
    lpre[tid] = s;
    __syncthreads();
    int val = s;
    #pragma unroll
    for (int off = 1; off < 256; off <<= 1) {
        int t = (tid >= off) ? lpre[tid - off] : 0;
        __syncthreads();
        val += t;
        lpre[tid] = val;
        __syncthreads();
    }
    int ex0 = val - s;                    // exclusive prefix of this chunk
    __syncthreads();                      // all reads of lpre done
    #pragma unroll
    for (int j = 0; j < 7; ++j) {
        int idx = base + j;
        if (idx < nsb) ldeg2[idx] = ex0 + loc[j];    // counts -> cursors
    }
    __syncthreads();

    // per-node outputs from sub-bucket prefix deltas
    if (tid < nn) {
        int p0 = ldeg2[tid * 8];
        int p1 = (tid == nn - 1) ? nb : ldeg2[tid * 8 + 8];
        int d = p1 - p0;
        offs[ns + tid] = lo + p0;
        float dr = (float)(d + 1);
        isq[ns + tid] = rsqrtf(dr);
        dinv[ns + tid] = 1.0f / dr;
    }
    if (tid == 0 && ne == N_NODES) offs[N_NODES] = hi;   // == N_EDGES
    __syncthreads();

    if (nb <= CAP) {
        for (int e = lo + tid; e < hi; e += 256) {
            unsigned int r = binned[e];
            unsigned int src = r & 0xffffffu;
            int p = atomicAdd(&ldeg2[(r >> 24) * 8 + src / SCLS_RANGE], 1);
            stag[p] = src;
        }
        __syncthreads();
        for (int j = tid; j < nb; j += 256)
            csr[lo + j] = stag[j];
    } else {
        for (int e = lo + tid; e < hi; e += 256) {
            unsigned int r = binned[e];
            unsigned int src = r & 0xffffffu;
            int p = atomicAdd(&ldeg2[(r >> 24) * 8 + src / SCLS_RANGE], 1);
            csr[lo + p] = src;
        }
    }
}

// ---------------------------------------------------------------------------
// Kernel 5: bf16 MFMA GEMM v4 (B staged in LDS per K-chunk, software-
// pipelined A stream). Verified-best gemm configuration.
// ---------------------------------------------------------------------------
__global__ __launch_bounds__(256, 4) void gemm_kernel(
    const float* __restrict__ x,
    const __hip_bfloat16* __restrict__ Wtf,
    const float* __restrict__ biasAll,
    const float* __restrict__ isq,
    unsigned short* __restrict__ hq,
    unsigned int* __restrict__ hg, unsigned short* __restrict__ hgi) {

    __shared__ __align__(16) unsigned char smem[33280];   // A 8704 + B 24576
    unsigned char* bchunk = smem + 8704;

    const int tid = threadIdx.x;
    const int node0 = blockIdx.x * 64;
    const int w = tid >> 6;
    const int lane = tid & 63;
    const int cl = lane & 15;
    const int kh = lane >> 4;

    float4v acc[12];
    #pragma unroll
    for (int s = 0; s < 12; ++s) acc[s] = (float4v){0.f, 0.f, 0.f, 0.f};

    int arr[4], acc_[4];
    #pragma unroll
    for (int j = 0; j < 4; ++j) {
        int f = j * 1024 + tid * 4;
        arr[j] = f >> 6; acc_[j] = f & 63;
    }

    float4v aR[4];
    #pragma unroll
    for (int j = 0; j < 4; ++j) {
        int node = node0 + arr[j];
        aR[j] = (node < N_NODES)
              ? *(const float4v*)(x + (size_t)node * 256 + 0 * 64 + acc_[j])
              : (float4v){0.f, 0.f, 0.f, 0.f};
    }

    #pragma unroll
    for (int c = 0; c < 4; ++c) {
        #pragma unroll
        for (int j = 0; j < 4; ++j) {
            __hip_bfloat16 b0 = __float2bfloat16(aR[j].x), b1 = __float2bfloat16(aR[j].y);
            __hip_bfloat16 b2 = __float2bfloat16(aR[j].z), b3 = __float2bfloat16(aR[j].w);
            unsigned int lo = (unsigned int)*(unsigned short*)&b0 | ((unsigned int)*(unsigned short*)&b1 << 16);
            unsigned int hi = (unsigned int)*(unsigned short*)&b2 | ((unsigned int)*(unsigned short*)&b3 << 16);
            *(uint2*)(smem + (size_t)arr[j] * 136 + (size_t)acc_[j] * 2) = make_uint2(lo, hi);
        }
        {
            const uint4v* bsrc = (const uint4v*)((const unsigned char*)Wtf + (size_t)c * 24576);
            uint4v* bdst = (uint4v*)bchunk;
            #pragma unroll
            for (int j = 0; j < 6; ++j)
                bdst[j * 256 + tid] = bsrc[j * 256 + tid];
        }
        __syncthreads();

        float4v aN[4];
        if (c < 3) {
            #pragma unroll
            for (int j = 0; j < 4; ++j) {
                int node = node0 + arr[j];
                aN[j] = (node < N_NODES)
                      ? *(const float4v*)(x + (size_t)node * 256 + (c + 1) * 64 + acc_[j])
                      : (float4v){0.f, 0.f, 0.f, 0.f};
            }
        }

        #pragma unroll
        for (int kkl = 0; kkl < 2; ++kkl) {
            short8 A = *(const short8*)(smem + (size_t)(16 * w + cl) * 136 + kkl * 64 + kh * 16);
            #pragma unroll
            for (int s = 0; s < 12; ++s) {
                short8 B = *(const short8*)(bchunk + (size_t)((kkl * 12 + s) * 64 + 4 * cl + kh) * 16);
                acc[s] = __builtin_amdgcn_mfma_f32_16x16x32_bf16(A, B, acc[s], 0, 0, 0);
            }
        }
        __syncthreads();
        if (c < 3) {
            #pragma unroll
            for (int j = 0; j < 4; ++j) aR[j] = aN[j];
        }
    }

    unsigned short* stq = (unsigned short*)smem;             // 8192 B
    unsigned int*   sth = (unsigned int*)(smem + 8192);      // 16384 B
    unsigned short* sti = (unsigned short*)(smem + 24576);   // 8192 B

    float sqv[4];
    #pragma unroll
    for (int r = 0; r < 4; ++r) {
        int node = node0 + 16 * w + kh * 4 + r;
        sqv[r] = (node < N_NODES) ? isq[node] : 0.f;
    }
    #pragma unroll
    for (int g = 0; g < 4; ++g) {
        int d = g * 16 + cl;
        float bias_hp = biasAll[d];
        float bias_lp = biasAll[d + 64];
        float bias_i  = biasAll[d + 128];
        #pragma unroll
        for (int r = 0; r < 4; ++r) {
            int nl = 16 * w + kh * 4 + r;
            float vhp = acc[g][r] + bias_hp;
            float vlp = acc[g + 4][r] + bias_lp;
            float vi  = acc[g + 8][r] + bias_i;
            stq[nl * 64 + d] = pack_fp8x2(vhp * sqv[r], vlp * sqv[r]);
            __hip_bfloat16 bh = __float2bfloat16(vhp);
            __hip_bfloat16 bl = __float2bfloat16(vlp);
            __hip_bfloat16 bb = __float2bfloat16(vi);
            sth[nl * 64 + d] =
                (unsigned int)*(unsigned short*)&bh | ((unsigned int)*(unsigned short*)&bl << 16);
            sti[nl * 64 + d] = *(unsigned short*)&bb;
        }
    }
    __syncthreads();

    int nvalid = N_NODES - node0; if (nvalid > 64) nvalid = 64;
    uint2* hq2 = (uint2*)(hq + (size_t)node0 * 64);
    uint2* stq2 = (uint2*)stq;
    #pragma unroll
    for (int j = 0; j < 4; ++j) {
        int idx = j * 256 + tid;
        if ((idx >> 4) < nvalid) hq2[idx] = stq2[idx];
    }
    uint4v* hg4 = (uint4v*)(hg + (size_t)node0 * 64);
    uint4v* sth4 = (uint4v*)sth;
    #pragma unroll
    for (int j = 0; j < 4; ++j) {
        int idx = j * 256 + tid;
        if ((idx >> 4) < nvalid) hg4[idx] = sth4[idx];
    }
    uint2* hgi2 = (uint2*)(hgi + (size_t)node0 * 64);
    uint2* sti2 = (uint2*)sti;
    #pragma unroll
    for (int j = 0; j < 4; ++j) {
        int idx = j * 256 + tid;
        if ((idx >> 4) < nvalid) hgi2[idx] = sti2[idx];
    }
}

// ---------------------------------------------------------------------------
// Kernel 6: fused aggregation + gates + log_softmax, v6: 2-deep gather
// pipeline — two 8-neighbor groups per iteration, both dwordx4 loads issued
// before either accumulate consumes (2x memory-level parallelism per wave).
// ---------------------------------------------------------------------------
__device__ __forceinline__ float wave_sum(float x) {
    #pragma unroll
    for (int off = 32; off > 0; off >>= 1) x += __shfl_xor(x, off);
    return x;
}
__device__ __forceinline__ float wave_max(float x) {
    #pragma unroll
    for (int off = 32; off > 0; off >>= 1) x = fmaxf(x, __shfl_xor(x, off));
    return x;
}

__global__ __launch_bounds__(256) void agg_kernel(
    const unsigned short* __restrict__ hq,
    const unsigned int* __restrict__ hg,
    const unsigned short* __restrict__ hgi,
    const int* __restrict__ offs,
    const unsigned int* __restrict__ csr,
    const float* __restrict__ isq,
    const float* __restrict__ dinv,
    const float* __restrict__ w_gh, const float* __restrict__ b_gh,
    const float* __restrict__ w_gl, const float* __restrict__ b_gl,
    const float* __restrict__ w_gi, const float* __restrict__ b_gi,
    float* __restrict__ out) {
    __shared__ float xfh[4][520];             // split planes, stride 65
    __shared__ float xfl[4][520];

    int wid = threadIdx.x >> 6;
    int v = blockIdx.x * 4 + wid;
    int lane = threadIdx.x & 63;
    if (v >= N_NODES) return;

    int start = offs[v], end = offs[v + 1];

    unsigned int gv = hg[(size_t)v * 64 + lane];
    unsigned int gvi = (unsigned int)hgi[(size_t)v * 64 + lane];
    float isqv = isq[v];
    float dv = dinv[v];
    float wgh = w_gh[lane], wgl = w_gl[lane], wgi = w_gi[lane];

    const int slot = lane >> 3;               // neighbor slot 0..7
    const int oct  = lane & 7;                // feature octet 0..7
    const unsigned oct16 = (unsigned)oct * 16u;
    const char* hqB = (const char*)hq;

    floatx2 a2[8];
    #pragma unroll
    for (int j = 0; j < 8; ++j) a2[j] = (floatx2){0.f, 0.f};

    for (int j0 = start; j0 < end; j0 += 64) {
        int m = end - j0; if (m > 64) m = 64;
        unsigned int uu = 0;
        if (lane < m) uu = csr[j0 + lane];
        int mfull = m & ~7;
        int k0 = 0;
        for (; k0 + 16 <= mfull; k0 += 16) {           // 2 groups: both loads in flight
            unsigned int u0 = __shfl(uu, k0 + slot);
            unsigned int u1 = __shfl(uu, k0 + 8 + slot);
            uint4v g0 = *(const uint4v*)(hqB + (size_t)(u0 * 128u + oct16));
            uint4v g1 = *(const uint4v*)(hqB + (size_t)(u1 * 128u + oct16));
            a2[0] += cvt2<false>(g0[0]); a2[1] += cvt2<true>(g0[0]);
            a2[2] += cvt2<false>(g0[1]); a2[3] += cvt2<true>(g0[1]);
            a2[4] += cvt2<false>(g0[2]); a2[5] += cvt2<true>(g0[2]);
            a2[6] += cvt2<false>(g0[3]); a2[7] += cvt2<true>(g0[3]);
            a2[0] += cvt2<false>(g1[0]); a2[1] += cvt2<true>(g1[0]);
            a2[2] += cvt2<false>(g1[1]); a2[3] += cvt2<true>(g1[1]);
            a2[4] += cvt2<false>(g1[2]); a2[5] += cvt2<true>(g1[2]);
            a2[6] += cvt2<false>(g1[3]); a2[7] += cvt2<true>(g1[3]);
        }
        if (k0 < mfull) {                              // one remaining full group
            unsigned int u = __shfl(uu, k0 + slot);
            uint4v g = *(const uint4v*)(hqB + (size_t)(u * 128u + oct16));
            a2[0] += cvt2<false>(g[0]); a2[1] += cvt2<true>(g[0]);
            a2[2] += cvt2<false>(g[1]); a2[3] += cvt2<true>(g[1]);
            a2[4] += cvt2<false>(g[2]); a2[5] += cvt2<true>(g[2]);
            a2[6] += cvt2<false>(g[3]); a2[7] += cvt2<true>(g[3]);
        }
        if (mfull < m) {                               // masked tail group
            int idx = mfull + slot;
            bool valid = idx < m;
            unsigned int u = __shfl(uu, valid ? idx : (m - 1));
            uint4v g = *(const uint4v*)(hqB + (size_t)(u * 128u + oct16));
            unsigned int zm = valid ? 0xffffffffu : 0u;
            #pragma unroll
            for (int dd = 0; dd < 4; ++dd) {
                unsigned int wv = g[dd] & zm;
                a2[2 * dd]     += cvt2<false>(wv);
                a2[2 * dd + 1] += cvt2<true>(wv);
            }
        }
    }

    #pragma unroll
    for (int j = 0; j < 8; ++j) {
        xfh[wid][slot * 65 + oct * 8 + j] = a2[j][0];
        xfl[wid][slot * 65 + oct * 8 + j] = a2[j][1];
    }
    float acc_hp = 0.f, acc_lp = 0.f;
    #pragma unroll
    for (int s = 0; s < 8; ++s) {
        acc_hp += xfh[wid][s * 65 + lane];
        acc_lp += xfl[wid][s * 65 + lane];
    }

    float agg_hp = acc_hp * isqv;
    float agg_lp = acc_lp * isqv;

    float hhp = __uint_as_float(gv << 16);
    float hlp = __uint_as_float(gv & 0xffff0000u);
    float hi  = __uint_as_float(gvi << 16);

    float Hhp = fmaxf(hhp - (agg_hp + dv * hhp), 0.f);
    float Hlp = fmaxf(agg_lp + dv * hlp, 0.f);
    float Hi  = fmaxf(hi, 0.f);

    // sh/sl dots share one packed-half2 butterfly; si separate f32.
    __half2 p2 = __floats2half2_rn(Hhp * wgh, Hlp * wgl);
    #pragma unroll
    for (int off = 32; off > 0; off >>= 1) {
        int o = __shfl_xor(*(int*)&p2, off);
        p2 = __hadd2(p2, *(__half2*)&o);
    }
    float sh = __low2float(p2) + b_gh[0];
    float sl = __high2float(p2) + b_gl[0];
    float si = wave_sum(Hi * wgi) + b_gi[0];

    float o = sh * Hhp + sl * Hlp + si * Hi;
    float mx = wave_max(o);
    float se = wave_sum(expf(o - mx));
    out[(size_t)v * 64 + lane] = o - mx - logf(se);
}

// ---------------------------------------------------------------------------
static inline size_t align256(size_t v) { return (v + 255) & ~(size_t)255; }

extern "C" void kernel_launch(void* const* d_in, const int* in_sizes, int n_in,
                              void* d_out, int out_size, void* d_ws, size_t ws_size,
                              hipStream_t stream) {
    const float* x    = (const float*)d_in[0];
    const void*  ei   = d_in[1];
    const float* Whp  = (const float*)d_in[2];
    const float* bhp  = (const float*)d_in[3];
    const float* Wlp  = (const float*)d_in[4];
    const float* blp  = (const float*)d_in[5];
    const float* Wi   = (const float*)d_in[6];
    const float* bi   = (const float*)d_in[7];
    const float* w_gh = (const float*)d_in[8];
    const float* b_gh = (const float*)d_in[9];
    const float* w_gl = (const float*)d_in[10];
    const float* b_gl = (const float*)d_in[11];
    const float* w_gi = (const float*)d_in[12];
    const float* b_gi = (const float*)d_in[13];
    float* out = (float*)d_out;

    const int N = N_NODES, E = N_EDGES;

    // workspace layout (256B-aligned regions); no zero-init needed anywhere.
    char* base = (char*)d_ws;
    size_t off = 0;
    int* offs = (int*)(base + off);            off = align256(off + (size_t)(N + 1) * 4);
    float* isq = (float*)(base + off);         off = align256(off + (size_t)N * 4);
    float* dinv = (float*)(base + off);        off = align256(off + (size_t)N * 4);
    int* hist = (int*)(base + off);            off = align256(off + (size_t)HTOT * 4);
    int* hb = (int*)(base + off);              off = align256(off + 512 * 4);
    int* pos = (int*)(base + off);             off = align256(off + (size_t)(HTOT + 1) * 4);
    unsigned int* binned = (unsigned int*)(base + off); off = align256(off + (size_t)E * 4);
    unsigned int* csr = (unsigned int*)(base + off); off = align256(off + (size_t)E * 4);
    float* biasAll = (float*)(base + off);     off = align256(off + 192 * 4);
    __hip_bfloat16* Wtf = (__hip_bfloat16*)(base + off); off = align256(off + 96 * 64 * 16);
    unsigned short* hq = (unsigned short*)(base + off); off = align256(off + (size_t)N * 64 * 2);
    unsigned int* hg = (unsigned int*)(base + off);   off = align256(off + (size_t)N * 64 * 4);
    unsigned short* hgi = (unsigned short*)(base + off); off = align256(off + (size_t)N * 64 * 2);

    hist_kernel<<<BINBLK, 256, 0, stream>>>(ei, hist);
    hscan1_kernel<<<HTOT / 256, 256, 0, stream>>>(hist, hb);
    hscan2_prep_kernel<<<13, 512, 0, stream>>>(hb, Whp, bhp, Wlp, blp, Wi, bi, Wtf, biasAll);
    hscan3_kernel<<<HTOT / 256, 256, 0, stream>>>(hist, hb, pos);
    bin_kernel<<<BINBLK, 256, 0, stream>>>(ei, pos, binned);
    fill_kernel<<<NBUK2, 256, 0, stream>>>(binned, pos, csr, offs, isq, dinv);
    gemm_kernel<<<(N + 63) / 64, 256, 0, stream>>>(x, Wtf, biasAll, isq, hq, hg, hgi);
    agg_kernel<<<(N + 3) / 4, 256, 0, stream>>>(hq, hg, hgi, offs, csr, isq, dinv,
                                                w_gh, b_gh, w_gl, b_gl, w_gi, b_gi, out);
}

// Round 24
// 157.250 us; speedup vs baseline: 1.1108x; 1.1108x over previous
//
#include <hip/hip_runtime.h>
#include <hip/hip_bf16.h>
#include <hip/hip_fp16.h>

#define N_NODES 100000
#define N_EDGES 3200000
#define IN_DIM  256
#define OUT_DIM 64
#define NBUK2   512
#define BRANGE  196                       // 512*196 = 100352 >= 100000
#define BINBLK  256                       // blocks in hist/bin (mapping MUST match)
#define CHUNK   (N_EDGES / BINBLK)        // 12500 (divisible by 4)
#define GRP     (CHUNK / 4)               // 3125 4-edge groups per block
#define HTOT    (NBUK2 * BINBLK)          // 131072
#define CAP     12288                     // LDS staging entries (48KB); mean 6250
#define SCLS_RANGE 12500                  // src-class granularity (8 classes)

typedef __attribute__((ext_vector_type(8))) short short8;
typedef __attribute__((ext_vector_type(4))) float float4v;
typedef __attribute__((ext_vector_type(2))) float floatx2;
typedef __attribute__((ext_vector_type(4))) unsigned int uint4v;
typedef __attribute__((ext_vector_type(2))) long long ll2;
typedef __attribute__((ext_vector_type(4))) int int4v;

// ---------------------------------------------------------------------------
// fp8 e4m3 pack/unpack (HW cvt on gfx950, software fallback)
// ---------------------------------------------------------------------------
__device__ __forceinline__ unsigned int enc_fp8_sw(float v) {
    unsigned int u = __float_as_uint(v);
    unsigned int s = (u >> 24) & 0x80u;
    unsigned int mag = u & 0x7fffffffu;
    unsigned int q;
    if (mag >= 0x43e00000u) q = 0x7e;
    else if (mag < 0x3c800000u) {
        float av = __uint_as_float(mag);
        q = (unsigned int)(av * 512.0f + 0.5f);
    } else {
        unsigned int mr = mag + 0x00080000u;
        unsigned int e = (mr >> 23) - 127 + 7;
        unsigned int m = (mr >> 20) & 7;
        q = (e << 3) | m;
        if (q > 0x7e) q = 0x7e;
    }
    return s | q;
}
__device__ __forceinline__ float dec_fp8_sw(unsigned int b) {
    unsigned int s = (b & 0x80u) << 24;
    unsigned int e = (b >> 3) & 15u, m = b & 7u;
    float f = (e == 0) ? (float)m * 0.001953125f
                       : __uint_as_float(((e + 120u) << 23) | (m << 20));
    return __uint_as_float(__float_as_uint(f) | s);
}

__device__ __forceinline__ unsigned short pack_fp8x2(float lo, float hi) {
#if __has_builtin(__builtin_amdgcn_cvt_pk_fp8_f32)
    int p = __builtin_amdgcn_cvt_pk_fp8_f32(lo, hi, 0, false);
    return (unsigned short)((unsigned int)p & 0xffffu);
#else
    return (unsigned short)(enc_fp8_sw(lo) | (enc_fp8_sw(hi) << 8));
#endif
}
template<bool HI>
__device__ __forceinline__ floatx2 cvt2(unsigned int w) {
#if __has_builtin(__builtin_amdgcn_cvt_pk_f32_fp8)
    return __builtin_amdgcn_cvt_pk_f32_fp8((int)w, HI);
#else
    unsigned int g = HI ? (w >> 16) : (w & 0xffffu);
    floatx2 r; r[0] = dec_fp8_sw(g & 0xffu); r[1] = dec_fp8_sw((g >> 8) & 0xffu);
    return r;
#endif
}

// ---------------------------------------------------------------------------
// Inline dtype detection. int64 input (values < 2^31) -> all odd 32-bit words
// of the first 8192 are 0.
// ---------------------------------------------------------------------------
__device__ __forceinline__ bool detect_is64(const void* ei) {
    int tid = threadIdx.x;
    const int* e32 = (const int*)ei;
    int found = 0;
    for (int w = 2 * tid + 1; w < 8192; w += 2 * blockDim.x)
        found |= (e32[w] != 0);
    return __syncthreads_or(found) == 0;
}

// ---------------------------------------------------------------------------
// Kernel 1: per-(bucket,block) histogram of dst. 4 edges/lane via 16B loads.
// ---------------------------------------------------------------------------
__global__ __launch_bounds__(256) void hist_kernel(
    const void* __restrict__ ei, int* __restrict__ hist) {
    __shared__ int lh[NBUK2];
    bool is64 = detect_is64(ei);
    int tid = threadIdx.x;
    for (int b = tid; b < NBUK2; b += 256) lh[b] = 0;
    __syncthreads();
    const int g0 = blockIdx.x * GRP, g1 = g0 + GRP;
    if (is64) {
        const long long* dptr = (const long long*)ei + N_EDGES;
        for (int g = g0 + tid; g < g1; g += 256) {
            int e = g * 4;
            ll2 d01 = *(const ll2*)(dptr + e);
            ll2 d23 = *(const ll2*)(dptr + e + 2);
            atomicAdd(&lh[(unsigned)(int)d01[0] / BRANGE], 1);
            atomicAdd(&lh[(unsigned)(int)d01[1] / BRANGE], 1);
            atomicAdd(&lh[(unsigned)(int)d23[0] / BRANGE], 1);
            atomicAdd(&lh[(unsigned)(int)d23[1] / BRANGE], 1);
        }
    } else {
        const int* dptr = (const int*)ei + N_EDGES;
        for (int g = g0 + tid; g < g1; g += 256) {
            int e = g * 4;
            int4v d = *(const int4v*)(dptr + e);
            atomicAdd(&lh[(unsigned)d[0] / BRANGE], 1);
            atomicAdd(&lh[(unsigned)d[1] / BRANGE], 1);
            atomicAdd(&lh[(unsigned)d[2] / BRANGE], 1);
            atomicAdd(&lh[(unsigned)d[3] / BRANGE], 1);
        }
    }
    __syncthreads();
    for (int b = tid; b < NBUK2; b += 256) hist[b * BINBLK + blockIdx.x] = lh[b];
}

// ---------------------------------------------------------------------------
// Kernels 2a/2b/2c: exclusive scan of hist[HTOT] -> pos. hscan2 fused with
// prep_w (block 0 = scan; blocks 1..12 = weight prep, fragment-linear layout).
// ---------------------------------------------------------------------------
__global__ __launch_bounds__(256) void hscan1_kernel(const int* __restrict__ hist,
                                                     int* __restrict__ hb) {
    __shared__ int red[256];
    int tid = threadIdx.x;
    red[tid] = hist[blockIdx.x * 256 + tid];
    __syncthreads();
    #pragma unroll
    for (int off = 128; off > 0; off >>= 1) {
        if (tid < off) red[tid] += red[tid + off];
        __syncthreads();
    }
    if (tid == 0) hb[blockIdx.x] = red[0];
}

__global__ __launch_bounds__(512) void hscan2_prep_kernel(
    int* __restrict__ hb,
    const float* __restrict__ Whp, const float* __restrict__ bhp,
    const float* __restrict__ Wlp, const float* __restrict__ blp,
    const float* __restrict__ Wi,  const float* __restrict__ bi,
    __hip_bfloat16* __restrict__ Wtf, float* __restrict__ biasAll) {
    __shared__ int sh[512];
    int tid = threadIdx.x;
    if (blockIdx.x == 0) {
        int v = hb[tid];
        sh[tid] = v;
        __syncthreads();
        int val = v;
        #pragma unroll
        for (int off = 1; off < 512; off <<= 1) {
            int t = (tid >= off) ? sh[tid - off] : 0;
            __syncthreads();
            val += t;
            sh[tid] = val;
            __syncthreads();
        }
        hb[tid] = val - v;                // exclusive block prefix
    } else {
        int gid = (blockIdx.x - 1) * 512 + tid;      // 0..6143 == 96*64-1
        int frag = gid >> 6, j = gid & 63;
        int kk = frag / 12, slot = frag - kk * 12;
        int cl = j >> 2, kh = j & 3;
        int col = slot * 16 + cl;
        const float* W = (col < 64) ? Whp : (col < 128) ? Wlp : Wi;
        int c2 = col & 63;
        int k0 = kk * 32 + kh * 8;
        unsigned short tmp[8];
        #pragma unroll
        for (int i = 0; i < 8; ++i) {
            __hip_bfloat16 bv = __float2bfloat16(W[(k0 + i) * 64 + c2]);
            tmp[i] = *(unsigned short*)&bv;
        }
        *(short8*)((unsigned short*)Wtf + (size_t)gid * 8) = *(short8*)tmp;
        if (gid < 192) {
            const float* b = (gid < 64) ? bhp : (gid < 128) ? blp : bi;
            biasAll[gid] = b[gid & 63];
        }
    }
}

__global__ __launch_bounds__(256) void hscan3_kernel(const int* __restrict__ hist,
                                                     const int* __restrict__ hb,
                                                     int* __restrict__ pos) {
    __shared__ int sh[256];
    int tid = threadIdx.x;
    int i = blockIdx.x * 256 + tid;
    int v = hist[i];
    sh[tid] = v;
    __syncthreads();
    int val = v;
    #pragma unroll
    for (int off = 1; off < 256; off <<= 1) {
        int t = (tid >= off) ? sh[tid - off] : 0;
        __syncthreads();
        val += t;
        sh[tid] = val;
        __syncthreads();
    }
    pos[i] = hb[blockIdx.x] + val - v;
    if (i == HTOT - 1) pos[HTOT] = N_EDGES;
}

// ---------------------------------------------------------------------------
// Kernel 3: bin edges by dst-bucket via LDS cursors. 4 edges/lane via 16B
// vector loads. 4B packed record src | lnode<<24.
// ---------------------------------------------------------------------------
__global__ __launch_bounds__(256) void bin_kernel(
    const void* __restrict__ ei,
    const int* __restrict__ pos, unsigned int* __restrict__ binned) {
    __shared__ int lcur[NBUK2];
    bool is64 = detect_is64(ei);
    int tid = threadIdx.x;
    for (int b = tid; b < NBUK2; b += 256) lcur[b] = pos[b * BINBLK + blockIdx.x];
    __syncthreads();
    const int g0 = blockIdx.x * GRP, g1 = g0 + GRP;
    if (is64) {
        const long long* sptr = (const long long*)ei;
        const long long* dptr = sptr + N_EDGES;
        for (int g = g0 + tid; g < g1; g += 256) {
            int e = g * 4;
            ll2 s01 = *(const ll2*)(sptr + e);
            ll2 s23 = *(const ll2*)(sptr + e + 2);
            ll2 d01 = *(const ll2*)(dptr + e);
            ll2 d23 = *(const ll2*)(dptr + e + 2);
            int ss[4] = {(int)s01[0], (int)s01[1], (int)s23[0], (int)s23[1]};
            int dd[4] = {(int)d01[0], (int)d01[1], (int)d23[0], (int)d23[1]};
            #pragma unroll
            for (int j = 0; j < 4; ++j) {
                int b = (int)((unsigned)dd[j] / BRANGE);
                int lnode = dd[j] - b * BRANGE;
                int p = atomicAdd(&lcur[b], 1);
                binned[p] = (unsigned)ss[j] | ((unsigned)lnode << 24);
            }
        }
    } else {
        const int* sptr = (const int*)ei;
        const int* dptr = sptr + N_EDGES;
        for (int g = g0 + tid; g < g1; g += 256) {
            int e = g * 4;
            int4v s = *(const int4v*)(sptr + e);
            int4v d = *(const int4v*)(dptr + e);
            #pragma unroll
            for (int j = 0; j < 4; ++j) {
                int b = (int)((unsigned)d[j] / BRANGE);
                int lnode = d[j] - b * BRANGE;
                int p = atomicAdd(&lcur[b], 1);
                binned[p] = (unsigned)s[j] | ((unsigned)lnode << 24);
            }
        }
    }
}

// ---------------------------------------------------------------------------
// Kernel 4: per-bucket CSR build fully in LDS. Sort key = lnode*8 + src-class.
// 4B packed input records. Also emits offs/isq/dinv.
// ---------------------------------------------------------------------------
__global__ __launch_bounds__(256) void fill_kernel(
    const unsigned int* __restrict__ binned, const int* __restrict__ pos,
    unsigned int* __restrict__ csr, int* __restrict__ offs,
    float* __restrict__ isq, float* __restrict__ dinv) {
    __shared__ int ldeg2[BRANGE * 8];     // per (node,src-class) counts->cursors
    __shared__ int lpre[256];
    __shared__ unsigned int stag[CAP];

    int b = blockIdx.x;
    int ns = b * BRANGE;
    if (ns >= N_NODES) return;
    int ne = ns + BRANGE; if (ne > N_NODES) ne = N_NODES;
    int nn = ne - ns;
    int nsb = nn * 8;                     // sub-bucket count
    int lo = pos[b * BINBLK];
    int hi = pos[(b + 1) * BINBLK];
    int nb = hi - lo;
    int tid = threadIdx.x;

    for (int i = tid; i < nsb; i += 256) ldeg2[i] = 0;
    __syncthreads();
    for (int e = lo + tid; e < hi; e += 256) {
        unsigned int r = binned[e];
        atomicAdd(&ldeg2[(r >> 24) * 8 + (r & 0xffffffu) / SCLS_RANGE], 1);
    }
    __syncthreads();

    // block-wide exclusive scan over nsb sub-buckets (7 elems/thread)
    int base = tid * 7;
    int loc[7];
    int s = 0;
    #pragma unroll
    for (int j = 0; j < 7; ++j) {
        int idx = base + j;
        int v = (idx < nsb) ? ldeg2[idx] : 0;
        loc[j] = s;
        s += v;
    }
    lpre[tid] = s;
    __syncthreads();
    int val = s;
    #pragma unroll
    for (int off = 1; off < 256; off <<= 1) {
        int t = (tid >= off) ? lpre[tid - off] : 0;
        __syncthreads();
        val += t;
        lpre[tid] = val;
        __syncthreads();
    }
    int ex0 = val - s;                    // exclusive prefix of this chunk
    __syncthreads();                      // all reads of lpre done
    #pragma unroll
    for (int j = 0; j < 7; ++j) {
        int idx = base + j;
        if (idx < nsb) ldeg2[idx] = ex0 + loc[j];    // counts -> cursors
    }
    __syncthreads();

    // per-node outputs from sub-bucket prefix deltas
    if (tid < nn) {
        int p0 = ldeg2[tid * 8];
        int p1 = (tid == nn - 1) ? nb : ldeg2[tid * 8 + 8];
        int d = p1 - p0;
        offs[ns + tid] = lo + p0;
        float dr = (float)(d + 1);
        isq[ns + tid] = rsqrtf(dr);
        dinv[ns + tid] = 1.0f / dr;
    }
    if (tid == 0 && ne == N_NODES) offs[N_NODES] = hi;   // == N_EDGES
    __syncthreads();

    if (nb <= CAP) {
        for (int e = lo + tid; e < hi; e += 256) {
            unsigned int r = binned[e];
            unsigned int src = r & 0xffffffu;
            int p = atomicAdd(&ldeg2[(r >> 24) * 8 + src / SCLS_RANGE], 1);
            stag[p] = src;
        }
        __syncthreads();
        for (int j = tid; j < nb; j += 256)
            csr[lo + j] = stag[j];
    } else {
        for (int e = lo + tid; e < hi; e += 256) {
            unsigned int r = binned[e];
            unsigned int src = r & 0xffffffu;
            int p = atomicAdd(&ldeg2[(r >> 24) * 8 + src / SCLS_RANGE], 1);
            csr[lo + p] = src;
        }
    }
}

// ---------------------------------------------------------------------------
// Kernel 5: bf16 MFMA GEMM v4 (B staged in LDS per K-chunk, software-
// pipelined A stream). Verified-best gemm configuration.
// ---------------------------------------------------------------------------
__global__ __launch_bounds__(256, 4) void gemm_kernel(
    const float* __restrict__ x,
    const __hip_bfloat16* __restrict__ Wtf,
    const float* __restrict__ biasAll,
    const float* __restrict__ isq,
    unsigned short* __restrict__ hq,
    unsigned int* __restrict__ hg, unsigned short* __restrict__ hgi) {

    __shared__ __align__(16) unsigned char smem[33280];   // A 8704 + B 24576
    unsigned char* bchunk = smem + 8704;

    const int tid = threadIdx.x;
    const int node0 = blockIdx.x * 64;
    const int w = tid >> 6;
    const int lane = tid & 63;
    const int cl = lane & 15;
    const int kh = lane >> 4;

    float4v acc[12];
    #pragma unroll
    for (int s = 0; s < 12; ++s) acc[s] = (float4v){0.f, 0.f, 0.f, 0.f};

    int arr[4], acc_[4];
    #pragma unroll
    for (int j = 0; j < 4; ++j) {
        int f = j * 1024 + tid * 4;
        arr[j] = f >> 6; acc_[j] = f & 63;
    }

    float4v aR[4];
    #pragma unroll
    for (int j = 0; j < 4; ++j) {
        int node = node0 + arr[j];
        aR[j] = (node < N_NODES)
              ? *(const float4v*)(x + (size_t)node * 256 + 0 * 64 + acc_[j])
              : (float4v){0.f, 0.f, 0.f, 0.f};
    }

    #pragma unroll
    for (int c = 0; c < 4; ++c) {
        #pragma unroll
        for (int j = 0; j < 4; ++j) {
            __hip_bfloat16 b0 = __float2bfloat16(aR[j].x), b1 = __float2bfloat16(aR[j].y);
            __hip_bfloat16 b2 = __float2bfloat16(aR[j].z), b3 = __float2bfloat16(aR[j].w);
            unsigned int lo = (unsigned int)*(unsigned short*)&b0 | ((unsigned int)*(unsigned short*)&b1 << 16);
            unsigned int hi = (unsigned int)*(unsigned short*)&b2 | ((unsigned int)*(unsigned short*)&b3 << 16);
            *(uint2*)(smem + (size_t)arr[j] * 136 + (size_t)acc_[j] * 2) = make_uint2(lo, hi);
        }
        {
            const uint4v* bsrc = (const uint4v*)((const unsigned char*)Wtf + (size_t)c * 24576);
            uint4v* bdst = (uint4v*)bchunk;
            #pragma unroll
            for (int j = 0; j < 6; ++j)
                bdst[j * 256 + tid] = bsrc[j * 256 + tid];
        }
        __syncthreads();

        float4v aN[4];
        if (c < 3) {
            #pragma unroll
            for (int j = 0; j < 4; ++j) {
                int node = node0 + arr[j];
                aN[j] = (node < N_NODES)
                      ? *(const float4v*)(x + (size_t)node * 256 + (c + 1) * 64 + acc_[j])
                      : (float4v){0.f, 0.f, 0.f, 0.f};
            }
        }

        #pragma unroll
        for (int kkl = 0; kkl < 2; ++kkl) {
            short8 A = *(const short8*)(smem + (size_t)(16 * w + cl) * 136 + kkl * 64 + kh * 16);
            #pragma unroll
            for (int s = 0; s < 12; ++s) {
                short8 B = *(const short8*)(bchunk + (size_t)((kkl * 12 + s) * 64 + 4 * cl + kh) * 16);
                acc[s] = __builtin_amdgcn_mfma_f32_16x16x32_bf16(A, B, acc[s], 0, 0, 0);
            }
        }
        __syncthreads();
        if (c < 3) {
            #pragma unroll
            for (int j = 0; j < 4; ++j) aR[j] = aN[j];
        }
    }

    unsigned short* stq = (unsigned short*)smem;             // 8192 B
    unsigned int*   sth = (unsigned int*)(smem + 8192);      // 16384 B
    unsigned short* sti = (unsigned short*)(smem + 24576);   // 8192 B

    float sqv[4];
    #pragma unroll
    for (int r = 0; r < 4; ++r) {
        int node = node0 + 16 * w + kh * 4 + r;
        sqv[r] = (node < N_NODES) ? isq[node] : 0.f;
    }
    #pragma unroll
    for (int g = 0; g < 4; ++g) {
        int d = g * 16 + cl;
        float bias_hp = biasAll[d];
        float bias_lp = biasAll[d + 64];
        float bias_i  = biasAll[d + 128];
        #pragma unroll
        for (int r = 0; r < 4; ++r) {
            int nl = 16 * w + kh * 4 + r;
            float vhp = acc[g][r] + bias_hp;
            float vlp = acc[g + 4][r] + bias_lp;
            float vi  = acc[g + 8][r] + bias_i;
            stq[nl * 64 + d] = pack_fp8x2(vhp * sqv[r], vlp * sqv[r]);
            __hip_bfloat16 bh = __float2bfloat16(vhp);
            __hip_bfloat16 bl = __float2bfloat16(vlp);
            __hip_bfloat16 bb = __float2bfloat16(vi);
            sth[nl * 64 + d] =
                (unsigned int)*(unsigned short*)&bh | ((unsigned int)*(unsigned short*)&bl << 16);
            sti[nl * 64 + d] = *(unsigned short*)&bb;
        }
    }
    __syncthreads();

    int nvalid = N_NODES - node0; if (nvalid > 64) nvalid = 64;
    uint2* hq2 = (uint2*)(hq + (size_t)node0 * 64);
    uint2* stq2 = (uint2*)stq;
    #pragma unroll
    for (int j = 0; j < 4; ++j) {
        int idx = j * 256 + tid;
        if ((idx >> 4) < nvalid) hq2[idx] = stq2[idx];
    }
    uint4v* hg4 = (uint4v*)(hg + (size_t)node0 * 64);
    uint4v* sth4 = (uint4v*)sth;
    #pragma unroll
    for (int j = 0; j < 4; ++j) {
        int idx = j * 256 + tid;
        if ((idx >> 4) < nvalid) hg4[idx] = sth4[idx];
    }
    uint2* hgi2 = (uint2*)(hgi + (size_t)node0 * 64);
    uint2* sti2 = (uint2*)sti;
    #pragma unroll
    for (int j = 0; j < 4; ++j) {
        int idx = j * 256 + tid;
        if ((idx >> 4) < nvalid) hgi2[idx] = sti2[idx];
    }
}

// ---------------------------------------------------------------------------
// Kernel 6: fused aggregation + gates + log_softmax, v7: 4-deep gather
// pipeline — up to four 8-neighbor groups' dwordx4 loads in flight before
// any accumulate consumes (deg~32 => one 4-deep iteration is the common case).
// ---------------------------------------------------------------------------
__device__ __forceinline__ float wave_sum(float x) {
    #pragma unroll
    for (int off = 32; off > 0; off >>= 1) x += __shfl_xor(x, off);
    return x;
}
__device__ __forceinline__ float wave_max(float x) {
    #pragma unroll
    for (int off = 32; off > 0; off >>= 1) x = fmaxf(x, __shfl_xor(x, off));
    return x;
}

__global__ __launch_bounds__(256) void agg_kernel(
    const unsigned short* __restrict__ hq,
    const unsigned int* __restrict__ hg,
    const unsigned short* __restrict__ hgi,
    const int* __restrict__ offs,
    const unsigned int* __restrict__ csr,
    const float* __restrict__ isq,
    const float* __restrict__ dinv,
    const float* __restrict__ w_gh, const float* __restrict__ b_gh,
    const float* __restrict__ w_gl, const float* __restrict__ b_gl,
    const float* __restrict__ w_gi, const float* __restrict__ b_gi,
    float* __restrict__ out) {
    __shared__ float xfh[4][520];             // split planes, stride 65
    __shared__ float xfl[4][520];

    int wid = threadIdx.x >> 6;
    int v = blockIdx.x * 4 + wid;
    int lane = threadIdx.x & 63;
    if (v >= N_NODES) return;

    int start = offs[v], end = offs[v + 1];

    unsigned int gv = hg[(size_t)v * 64 + lane];
    unsigned int gvi = (unsigned int)hgi[(size_t)v * 64 + lane];
    float isqv = isq[v];
    float dv = dinv[v];
    float wgh = w_gh[lane], wgl = w_gl[lane], wgi = w_gi[lane];

    const int slot = lane >> 3;               // neighbor slot 0..7
    const int oct  = lane & 7;                // feature octet 0..7
    const unsigned oct16 = (unsigned)oct * 16u;
    const char* hqB = (const char*)hq;

    floatx2 a2[8];
    #pragma unroll
    for (int j = 0; j < 8; ++j) a2[j] = (floatx2){0.f, 0.f};

    for (int j0 = start; j0 < end; j0 += 64) {
        int m = end - j0; if (m > 64) m = 64;
        unsigned int uu = 0;
        if (lane < m) uu = csr[j0 + lane];
        int mfull = m & ~7;
        int k0 = 0;
        for (; k0 + 32 <= mfull; k0 += 32) {           // 4 groups: 4 loads in flight
            unsigned int u0 = __shfl(uu, k0 + slot);
            unsigned int u1 = __shfl(uu, k0 + 8 + slot);
            unsigned int u2 = __shfl(uu, k0 + 16 + slot);
            unsigned int u3 = __shfl(uu, k0 + 24 + slot);
            uint4v g0 = *(const uint4v*)(hqB + (size_t)(u0 * 128u + oct16));
            uint4v g1 = *(const uint4v*)(hqB + (size_t)(u1 * 128u + oct16));
            uint4v g2 = *(const uint4v*)(hqB + (size_t)(u2 * 128u + oct16));
            uint4v g3 = *(const uint4v*)(hqB + (size_t)(u3 * 128u + oct16));
            a2[0] += cvt2<false>(g0[0]); a2[1] += cvt2<true>(g0[0]);
            a2[2] += cvt2<false>(g0[1]); a2[3] += cvt2<true>(g0[1]);
            a2[4] += cvt2<false>(g0[2]); a2[5] += cvt2<true>(g0[2]);
            a2[6] += cvt2<false>(g0[3]); a2[7] += cvt2<true>(g0[3]);
            a2[0] += cvt2<false>(g1[0]); a2[1] += cvt2<true>(g1[0]);
            a2[2] += cvt2<false>(g1[1]); a2[3] += cvt2<true>(g1[1]);
            a2[4] += cvt2<false>(g1[2]); a2[5] += cvt2<true>(g1[2]);
            a2[6] += cvt2<false>(g1[3]); a2[7] += cvt2<true>(g1[3]);
            a2[0] += cvt2<false>(g2[0]); a2[1] += cvt2<true>(g2[0]);
            a2[2] += cvt2<false>(g2[1]); a2[3] += cvt2<true>(g2[1]);
            a2[4] += cvt2<false>(g2[2]); a2[5] += cvt2<true>(g2[2]);
            a2[6] += cvt2<false>(g2[3]); a2[7] += cvt2<true>(g2[3]);
            a2[0] += cvt2<false>(g3[0]); a2[1] += cvt2<true>(g3[0]);
            a2[2] += cvt2<false>(g3[1]); a2[3] += cvt2<true>(g3[1]);
            a2[4] += cvt2<false>(g3[2]); a2[5] += cvt2<true>(g3[2]);
            a2[6] += cvt2<false>(g3[3]); a2[7] += cvt2<true>(g3[3]);
        }
        for (; k0 + 16 <= mfull; k0 += 16) {           // 2 groups
            unsigned int u0 = __shfl(uu, k0 + slot);
            unsigned int u1 = __shfl(uu, k0 + 8 + slot);
            uint4v g0 = *(const uint4v*)(hqB + (size_t)(u0 * 128u + oct16));
            uint4v g1 = *(const uint4v*)(hqB + (size_t)(u1 * 128u + oct16));
            a2[0] += cvt2<false>(g0[0]); a2[1] += cvt2<true>(g0[0]);
            a2[2] += cvt2<false>(g0[1]); a2[3] += cvt2<true>(g0[1]);
            a2[4] += cvt2<false>(g0[2]); a2[5] += cvt2<true>(g0[2]);
            a2[6] += cvt2<false>(g0[3]); a2[7] += cvt2<true>(g0[3]);
            a2[0] += cvt2<false>(g1[0]); a2[1] += cvt2<true>(g1[0]);
            a2[2] += cvt2<false>(g1[1]); a2[3] += cvt2<true>(g1[1]);
            a2[4] += cvt2<false>(g1[2]); a2[5] += cvt2<true>(g1[2]);
            a2[6] += cvt2<false>(g1[3]); a2[7] += cvt2<true>(g1[3]);
        }
        if (k0 < mfull) {                              // one remaining full group
            unsigned int u = __shfl(uu, k0 + slot);
            uint4v g = *(const uint4v*)(hqB + (size_t)(u * 128u + oct16));
            a2[0] += cvt2<false>(g[0]); a2[1] += cvt2<true>(g[0]);
            a2[2] += cvt2<false>(g[1]); a2[3] += cvt2<true>(g[1]);
            a2[4] += cvt2<false>(g[2]); a2[5] += cvt2<true>(g[2]);
            a2[6] += cvt2<false>(g[3]); a2[7] += cvt2<true>(g[3]);
        }
        if (mfull < m) {                               // masked tail group
            int idx = mfull + slot;
            bool valid = idx < m;
            unsigned int u = __shfl(uu, valid ? idx : (m - 1));
            uint4v g = *(const uint4v*)(hqB + (size_t)(u * 128u + oct16));
            unsigned int zm = valid ? 0xffffffffu : 0u;
            #pragma unroll
            for (int dd = 0; dd < 4; ++dd) {
                unsigned int wv = g[dd] & zm;
                a2[2 * dd]     += cvt2<false>(wv);
                a2[2 * dd + 1] += cvt2<true>(wv);
            }
        }
    }

    #pragma unroll
    for (int j = 0; j < 8; ++j) {
        xfh[wid][slot * 65 + oct * 8 + j] = a2[j][0];
        xfl[wid][slot * 65 + oct * 8 + j] = a2[j][1];
    }
    float acc_hp = 0.f, acc_lp = 0.f;
    #pragma unroll
    for (int s = 0; s < 8; ++s) {
        acc_hp += xfh[wid][s * 65 + lane];
        acc_lp += xfl[wid][s * 65 + lane];
    }

    float agg_hp = acc_hp * isqv;
    float agg_lp = acc_lp * isqv;

    float hhp = __uint_as_float(gv << 16);
    float hlp = __uint_as_float(gv & 0xffff0000u);
    float hi  = __uint_as_float(gvi << 16);

    float Hhp = fmaxf(hhp - (agg_hp + dv * hhp), 0.f);
    float Hlp = fmaxf(agg_lp + dv * hlp, 0.f);
    float Hi  = fmaxf(hi, 0.f);

    // sh/sl dots share one packed-half2 butterfly; si separate f32.
    __half2 p2 = __floats2half2_rn(Hhp * wgh, Hlp * wgl);
    #pragma unroll
    for (int off = 32; off > 0; off >>= 1) {
        int o = __shfl_xor(*(int*)&p2, off);
        p2 = __hadd2(p2, *(__half2*)&o);
    }
    float sh = __low2float(p2) + b_gh[0];
    float sl = __high2float(p2) + b_gl[0];
    float si = wave_sum(Hi * wgi) + b_gi[0];

    float o = sh * Hhp + sl * Hlp + si * Hi;
    float mx = wave_max(o);
    float se = wave_sum(expf(o - mx));
    out[(size_t)v * 64 + lane] = o - mx - logf(se);
}

// ---------------------------------------------------------------------------
static inline size_t align256(size_t v) { return (v + 255) & ~(size_t)255; }

extern "C" void kernel_launch(void* const* d_in, const int* in_sizes, int n_in,
                              void* d_out, int out_size, void* d_ws, size_t ws_size,
                              hipStream_t stream) {
    const float* x    = (const float*)d_in[0];
    const void*  ei   = d_in[1];
    const float* Whp  = (const float*)d_in[2];
    const float* bhp  = (const float*)d_in[3];
    const float* Wlp  = (const float*)d_in[4];
    const float* blp  = (const float*)d_in[5];
    const float* Wi   = (const float*)d_in[6];
    const float* bi   = (const float*)d_in[7];
    const float* w_gh = (const float*)d_in[8];
    const float* b_gh = (const float*)d_in[9];
    const float* w_gl = (const float*)d_in[10];
    const float* b_gl = (const float*)d_in[11];
    const float* w_gi = (const float*)d_in[12];
    const float* b_gi = (const float*)d_in[13];
    float* out = (float*)d_out;

    const int N = N_NODES, E = N_EDGES;

    // workspace layout (256B-aligned regions); no zero-init needed anywhere.
    char* base = (char*)d_ws;
    size_t off = 0;
    int* offs = (int*)(base + off);            off = align256(off + (size_t)(N + 1) * 4);
    float* isq = (float*)(base + off);         off = align256(off + (size_t)N * 4);
    float* dinv = (float*)(base + off);        off = align256(off + (size_t)N * 4);
    int* hist = (int*)(base + off);            off = align256(off + (size_t)HTOT * 4);
    int* hb = (int*)(base + off);              off = align256(off + 512 * 4);
    int* pos = (int*)(base + off);             off = align256(off + (size_t)(HTOT + 1) * 4);
    unsigned int* binned = (unsigned int*)(base + off); off = align256(off + (size_t)E * 4);
    unsigned int* csr = (unsigned int*)(base + off); off = align256(off + (size_t)E * 4);
    float* biasAll = (float*)(base + off);     off = align256(off + 192 * 4);
    __hip_bfloat16* Wtf = (__hip_bfloat16*)(base + off); off = align256(off + 96 * 64 * 16);
    unsigned short* hq = (unsigned short*)(base + off); off = align256(off + (size_t)N * 64 * 2);
    unsigned int* hg = (unsigned int*)(base + off);   off = align256(off + (size_t)N * 64 * 4);
    unsigned short* hgi = (unsigned short*)(base + off); off = align256(off + (size_t)N * 64 * 2);

    hist_kernel<<<BINBLK, 256, 0, stream>>>(ei, hist);
    hscan1_kernel<<<HTOT / 256, 256, 0, stream>>>(hist, hb);
    hscan2_prep_kernel<<<13, 512, 0, stream>>>(hb, Whp, bhp, Wlp, blp, Wi, bi, Wtf, biasAll);
    hscan3_kernel<<<HTOT / 256, 256, 0, stream>>>(hist, hb, pos);
    bin_kernel<<<BINBLK, 256, 0, stream>>>(ei, pos, binned);
    fill_kernel<<<NBUK2, 256, 0, stream>>>(binned, pos, csr, offs, isq, dinv);
    gemm_kernel<<<(N + 63) / 64, 256, 0, stream>>>(x, Wtf, biasAll, isq, hq, hg, hgi);
    agg_kernel<<<(N + 3) / 4, 256, 0, stream>>>(hq, hg, hgi, offs, csr, isq, dinv,
                                                w_gh, b_gh, w_gl, b_gl, w_gi, b_gi, out);
}